// Round 1
// baseline (21515.913 us; speedup 1.0000x reference)
//
#include <hip/hip_runtime.h>
#include <hip/hip_bf16.h>

#define SEQ 8192
#define HID 2048
#define NBLK 64        // persistent scan blocks (distinct CUs -> co-resident)
#define ROWS 32        // Wh rows per block (NBLK*ROWS == HID)

typedef short short8 __attribute__((ext_vector_type(8)));
typedef float floatx4 __attribute__((ext_vector_type(4)));
typedef unsigned uintx4 __attribute__((ext_vector_type(4)));

// Split 8 consecutive f32 into bf16 hi + bf16 lo fragments (RNE rounding).
__device__ __forceinline__ void split_bf16(const float* __restrict__ p,
                                           short8& hi, short8& lo) {
    const float4 f0 = *(const float4*)p;
    const float4 f1 = *(const float4*)(p + 4);
    const float f[8] = {f0.x, f0.y, f0.z, f0.w, f1.x, f1.y, f1.z, f1.w};
#pragma unroll
    for (int e = 0; e < 8; ++e) {
        const unsigned u = __float_as_uint(f[e]);
        const unsigned r = (u + 0x7fffu + ((u >> 16) & 1u)) & 0xffff0000u;
        hi[e] = (short)(r >> 16);
        const float l = f[e] - __uint_as_float(r);
        const unsigned ul = __float_as_uint(l);
        lo[e] = (short)((ul + 0x7fffu + ((ul >> 16) & 1u)) >> 16);
    }
}

// ---------------------------------------------------------------------------
// Kernel 1: xp[s,h] = sum_k x[s,k]*Wi[h,k] + bi[h]  (f32 in/out, bf16-split
// MFMA: 3 products per k-chunk, ~1e-4 abs error).
// ---------------------------------------------------------------------------
__global__ __launch_bounds__(256) void xproj_gemm(
    const float* __restrict__ x,       // [SEQ, HID]
    const float* __restrict__ Wi,      // [HID, HID]
    const float* __restrict__ bi,      // [HID]
    float* __restrict__ xp)            // [SEQ, HID]
{
    const int bn = blockIdx.x;
    const int bm = blockIdx.y;
    const int tid = threadIdx.x;
    const int wave = tid >> 6;
    const int lane = tid & 63;
    const int wM = wave & 1, wN = wave >> 1;
    const int l16 = lane & 15, kq = lane >> 4;
    const int m0 = bm * 64 + wM * 32;
    const int n0 = bn * 64 + wN * 32;

    floatx4 acc00 = {0.f,0.f,0.f,0.f}, acc01 = {0.f,0.f,0.f,0.f};
    floatx4 acc10 = {0.f,0.f,0.f,0.f}, acc11 = {0.f,0.f,0.f,0.f};

    const float* xA0 = x  + (size_t)(m0 + l16)      * HID;
    const float* xA1 = x  + (size_t)(m0 + 16 + l16) * HID;
    const float* wB0 = Wi + (size_t)(n0 + l16)      * HID;
    const float* wB1 = Wi + (size_t)(n0 + 16 + l16) * HID;

    for (int kc = 0; kc < HID; kc += 32) {
        const int k = kc + kq * 8;
        short8 a0h, a0l, a1h, a1l, b0h, b0l, b1h, b1l;
        split_bf16(xA0 + k, a0h, a0l);
        split_bf16(xA1 + k, a1h, a1l);
        split_bf16(wB0 + k, b0h, b0l);
        split_bf16(wB1 + k, b1h, b1l);
        acc00 = __builtin_amdgcn_mfma_f32_16x16x32_bf16(a0h, b0h, acc00, 0,0,0);
        acc00 = __builtin_amdgcn_mfma_f32_16x16x32_bf16(a0l, b0h, acc00, 0,0,0);
        acc00 = __builtin_amdgcn_mfma_f32_16x16x32_bf16(a0h, b0l, acc00, 0,0,0);
        acc01 = __builtin_amdgcn_mfma_f32_16x16x32_bf16(a0h, b1h, acc01, 0,0,0);
        acc01 = __builtin_amdgcn_mfma_f32_16x16x32_bf16(a0l, b1h, acc01, 0,0,0);
        acc01 = __builtin_amdgcn_mfma_f32_16x16x32_bf16(a0h, b1l, acc01, 0,0,0);
        acc10 = __builtin_amdgcn_mfma_f32_16x16x32_bf16(a1h, b0h, acc10, 0,0,0);
        acc10 = __builtin_amdgcn_mfma_f32_16x16x32_bf16(a1l, b0h, acc10, 0,0,0);
        acc10 = __builtin_amdgcn_mfma_f32_16x16x32_bf16(a1h, b0l, acc10, 0,0,0);
        acc11 = __builtin_amdgcn_mfma_f32_16x16x32_bf16(a1h, b1h, acc11, 0,0,0);
        acc11 = __builtin_amdgcn_mfma_f32_16x16x32_bf16(a1l, b1h, acc11, 0,0,0);
        acc11 = __builtin_amdgcn_mfma_f32_16x16x32_bf16(a1h, b1l, acc11, 0,0,0);
    }

    const float bi0 = bi[n0 + l16];
    const float bi1 = bi[n0 + 16 + l16];
#pragma unroll
    for (int reg = 0; reg < 4; ++reg) {
        const int mlo = m0 + kq * 4 + reg;
        const int mhi = mlo + 16;
        xp[(size_t)mlo * HID + n0 + l16]      = acc00[reg] + bi0;
        xp[(size_t)mlo * HID + n0 + 16 + l16] = acc01[reg] + bi1;
        xp[(size_t)mhi * HID + n0 + l16]      = acc10[reg] + bi0;
        xp[(size_t)mhi * HID + n0 + 16 + l16] = acc11[reg] + bi1;
    }
}

// ---------------------------------------------------------------------------
// Kernel 2: persistent recurrence, one-hop tagged-data exchange.
// Round-6 structure (round-5 + packed exchange):
//  - exchange word u64 = [tag:13 | h0:25 | h1:25(+1 spare)], two h values per
//    word at sign+8exp+16mant (RNE trunc of f32, rel err 2^-17 ~ 8e-6).
//    SEQ = 8192 = 2^13 so 13-bit tags never wrap.
//  - poll = ONE global_load_dwordx4 sc0 sc1 per thread (8 KB/block/round,
//    half of round-5's 16 KB -> half the LLC line flood per retry round)
//  - LDS-only barrier (s_waitcnt lgkmcnt(0); s_barrier): global stores stay
//    in flight across the step boundary (no vmcnt(0) drain -> no HBM-ack
//    on the critical path)
//  - out[] store for step t-1 issued at step t post-detect (fully hidden)
//  - xp prefetched one step ahead
// Safety: tag chain orders everything. A wave's step-t hbuf store data-
// depends on its step-t LDS reads; step-t+1 staging polls ALL slots (incl.
// own block's rows), so all waves' reads are complete before any LDS write.
// Buffer-parity reuse is safe: tag t overwrites tag t-2 only after every
// block stored t-1, which implies every block finished polling t-2.
// ws poison 0xAAAAAAAA -> tag field 0x1555 = 5461; first use of each parity
// buffer polls for tag 0 or 1, so poison never false-matches.
// ---------------------------------------------------------------------------

// pack two f32 in [-1,1] + 13-bit tag into one u64 (25-bit RNE truncation)
__device__ __forceinline__ unsigned long long pack2(float h0, float h1,
                                                    unsigned tag) {
    const unsigned u0 = __float_as_uint(h0);
    const unsigned u1 = __float_as_uint(h1);
    const unsigned r0 = (u0 + 0x3Fu + ((u0 >> 7) & 1u)) >> 7;   // 25 bits
    const unsigned r1 = (u1 + 0x3Fu + ((u1 >> 7) & 1u)) >> 7;   // 25 bits
    return ((unsigned long long)tag << 51) |
           ((unsigned long long)r0 << 25) |
           (unsigned long long)r1;
}

__global__ __launch_bounds__(512, 1) void rnn_scan(
    const float* __restrict__ Wh,    // [HID, HID]
    const float* __restrict__ bh,    // [HID]
    const float* __restrict__ xp,    // [SEQ, HID]
    unsigned long long* hbuf,        // [2][1024] packed tagged exchange
    float* out)                      // [SEQ*HID + HID]
{
    __shared__ float h_lds[HID];

    const int b   = blockIdx.x;
    const int tid = threadIdx.x;
    const int wv  = tid >> 6;        // wave = row group (4 rows each)
    const int L   = tid & 63;
    const int row = b * ROWS + wv * 4 + L;   // meaningful when L < 4

    // one-time: Wh rows -> registers. Lane L covers cols 256*j+4*L+{0..3}.
    floatx4 w[4][8];
#pragma unroll
    for (int r = 0; r < 4; ++r) {
        const size_t rr = (size_t)(b * ROWS + wv * 4 + r);
#pragma unroll
        for (int j = 0; j < 8; ++j)
            w[r][j] = *(const floatx4*)(Wh + rr * HID + 256 * j + 4 * L);
    }
    const float bh_l = (L < 4) ? bh[row] : 0.f;

    float xp_cur = (L < 4) ? xp[row] : 0.f;   // step 0
    float prev_h = 0.f;

    for (int t = 0; t < SEQ; ++t) {
        float acc[4] = {0.f, 0.f, 0.f, 0.f};

        if (t > 0) {
            // slot s holds rows {2s, 2s+1}; thread polls slots {2tid, 2tid+1}
            const unsigned long long* src =
                hbuf + ((t - 1) & 1) * 1024 + 2 * tid;
            const unsigned want = (unsigned)(t - 1);
            uintx4 p;   // [w0.lo, w0.hi, w1.lo, w1.hi]
            do {   // one round-trip per retry round; wide + coalesced
                asm volatile(
                    "global_load_dwordx4 %0, %1, off sc0 sc1\n\t"
                    "s_waitcnt vmcnt(0)"
                    : "=&v"(p)
                    : "v"(src)
                    : "memory");
            } while (((p[1] >> 19) != want) | ((p[3] >> 19) != want));
            // unpack: f0 = bits[49:25]<<7 rebuilt from (hi,lo), f1 = lo<<7
            float4 hv;
            hv.x = __uint_as_float((p[1] << 14) | ((p[0] >> 25) << 7));
            hv.y = __uint_as_float(p[0] << 7);
            hv.z = __uint_as_float((p[3] << 14) | ((p[2] >> 25) << 7));
            hv.w = __uint_as_float(p[2] << 7);
            *(float4*)&h_lds[4 * tid] = hv;
            // deferred out[] store for step t-1: ~1800cy to retire unseen
            if (L < 4) out[(size_t)(t - 1) * HID + row] = prev_h;
            // LDS-only barrier: do NOT drain vmcnt (stores stay in flight)
            asm volatile("s_waitcnt lgkmcnt(0)\n\ts_barrier" ::: "memory");
        }

        // prefetch next step's xp (used next iteration; fully hidden)
        float xp_next = 0.f;
        if (L < 4 && t + 1 < SEQ) xp_next = xp[(size_t)(t + 1) * HID + row];

        if (t > 0) {
            // dot: 4 rows x 32 cols per lane (b128 LDS reads, conflict-free)
#pragma unroll
            for (int j = 0; j < 8; ++j) {
                const float4 hv = *(const float4*)&h_lds[256 * j + 4 * L];
#pragma unroll
                for (int r = 0; r < 4; ++r) {
                    acc[r] += w[r][j][0] * hv.x;
                    acc[r] += w[r][j][1] * hv.y;
                    acc[r] += w[r][j][2] * hv.z;
                    acc[r] += w[r][j][3] * hv.w;
                }
            }
        }

        // 64-lane butterfly reduce
#pragma unroll
        for (int off = 32; off > 0; off >>= 1) {
#pragma unroll
            for (int r = 0; r < 4; ++r) acc[r] += __shfl_xor(acc[r], off, 64);
        }

        if (L < 4) {
            float a = acc[L] + xp_cur + bh_l;
            a = fminf(fmaxf(a, -15.f), 15.f);
            const float e = __expf(2.f * a);
            const float hval = (e - 1.f) / (e + 1.f);
            // pair rows (0,1) on lane 0, (2,3) on lane 2 via one xor-shuffle
            const float hpartner = __shfl_xor(hval, 1, 64);
            if ((L & 1) == 0) {
                const unsigned long long w64 =
                    pack2(hval, hpartner, (unsigned)t);
                __hip_atomic_store(
                    &hbuf[(t & 1) * 1024 + b * 16 + wv * 2 + (L >> 1)], w64,
                    __ATOMIC_RELAXED, __HIP_MEMORY_SCOPE_AGENT);
            }
            prev_h = hval;
        }
        xp_cur = xp_next;
    }

    if (L < 4) {
        out[(size_t)(SEQ - 1) * HID + row] = prev_h;   // last step's output
        out[(size_t)SEQ * HID + row]       = prev_h;   // h_n
    }
}

// ---------------------------------------------------------------------------
extern "C" void kernel_launch(void* const* d_in, const int* in_sizes, int n_in,
                              void* d_out, int out_size, void* d_ws, size_t ws_size,
                              hipStream_t stream) {
    const float* x  = (const float*)d_in[0];   // [8192,2048] f32
    const float* Wi = (const float*)d_in[1];   // [2048,2048] f32
    const float* bi = (const float*)d_in[2];   // [2048] f32
    const float* Wh = (const float*)d_in[3];   // [2048,2048] f32
    const float* bh = (const float*)d_in[4];   // [2048] f32
    float* out      = (float*)d_out;           // outputs ++ h_n

    // ws: xp f32 [SEQ*HID] (64 MB) | hbuf u64 [2*1024] (16 KB)
    float* xp = (float*)d_ws;
    unsigned long long* hbuf = (unsigned long long*)(xp + (size_t)SEQ * HID);

    xproj_gemm<<<dim3(HID / 64, SEQ / 64), 256, 0, stream>>>(x, Wi, bi, xp);
    rnn_scan<<<NBLK, 512, 0, stream>>>(Wh, bh, xp, hbuf, out);
}